// Round 12
// baseline (230.275 us; speedup 1.0000x reference)
//
#include <hip/hip_runtime.h>
#include <math.h>

#define Bn 2
#define Nn 20000
#define Cn 512
#define Sn 128
#define Hn 8
#define Dn 64
#define En 320000
#define EPSf 1e-6f
#define NB64 313   // ceil(20000/64)
#define NB128 157  // ceil(20000/128)
#define NSCAN 20   // ceil(20000/1024)

#define S_CHUNK 320
#define S_KB 63        // 63*320 = 20160 >= 20000
#define G_CHUNK 128
#define G_KB 157       // 157*128 = 20096 >= 20000

typedef __attribute__((ext_vector_type(4))) float f32x4;
typedef __attribute__((ext_vector_type(8))) short s16x8;

__device__ __forceinline__ unsigned short f2bf(float f) {
    unsigned u = __float_as_uint(f);
    return (unsigned short)((u + 0x7fffu + ((u >> 16) & 1u)) >> 16);
}
__device__ __forceinline__ float bf2f(unsigned short h) {
    return __uint_as_float(((unsigned)h) << 16);
}

// Swizzled LDS byte offset for a [rows][64 k] bf16 tile (rows<=128).
__device__ __forceinline__ unsigned lds_off(int row, int n) {
    unsigned ch = ((((unsigned)n >> 3) ^ ((unsigned)row & 7u) ^ (((unsigned)row >> 3) & 7u)) & 7u);
    return (unsigned)row * 128u + ch * 16u + ((unsigned)n & 7u) * 2u;
}

// ---- stage [128 rows][64 k] bf16 tile from bf16 row-major source --------------
__device__ __forceinline__ void stage_bf16tile(
    const unsigned short* __restrict__ src, int stride, int nvalid, unsigned* dst, int t)
{
    #pragma unroll
    for (int l = 0; l < 2; l++) {
        int task = t + l * 256;
        int row = task >> 2, seg = task & 3;
        s16x8 a = {0,0,0,0,0,0,0,0}, b = {0,0,0,0,0,0,0,0};
        if (row < nvalid) {
            a = *(const s16x8*)(src + (size_t)row * stride + seg * 16);
            b = *(const s16x8*)(src + (size_t)row * stride + seg * 16 + 8);
        }
        *(s16x8*)((char*)dst + lds_off(row, seg * 16)) = a;
        *(s16x8*)((char*)dst + lds_off(row, seg * 16 + 8)) = b;
    }
}

// ---------------- prep: weight transposes + workspace zeroing ------------------
__global__ __launch_bounds__(256) void k_prepW(
    const float* __restrict__ Ws, const float* __restrict__ Wq,
    const float* __restrict__ Wk, const float* __restrict__ Wv,
    const float* __restrict__ Wo, unsigned short* __restrict__ WsT,
    unsigned short* __restrict__ WT, int* __restrict__ zeroU,
    float* __restrict__ wsum)
{
    __shared__ float tile[32][33];
    int t = threadIdx.x;
    int z = blockIdx.z;
    int k0 = blockIdx.x * 32;
    int c0 = blockIdx.y * 32;
    const float* W;
    unsigned short* dst;
    int ncols;
    if (z == 0) {
        if (c0 >= Sn) {
            int idx = (((int)blockIdx.y - 4) * 16 + (int)blockIdx.x) * 256 + t;
            if (idx < 40064) zeroU[idx] = 0;                 // deg + cursor
            else if (idx < 40064 + Bn * Sn) wsum[idx - 40064] = 0.f;
            return;
        }
        W = Ws; dst = WsT; ncols = Sn;
    } else {
        W = (z == 1) ? Wq : (z == 2) ? Wk : (z == 3) ? Wv : Wo;
        dst = WT + (size_t)(z - 1) * Cn * Cn; ncols = Cn;
    }
    #pragma unroll
    for (int l = 0; l < 4; l++) {
        int idx = t + l * 256;
        int r = idx >> 5, c = idx & 31;
        tile[r][c] = W[(size_t)(k0 + r) * ncols + c0 + c];
    }
    __syncthreads();
    #pragma unroll
    for (int l = 0; l < 4; l++) {
        int idx = t + l * 256;
        int r = idx >> 5, c = idx & 31;
        dst[(size_t)(c0 + r) * Cn + k0 + c] = f2bf(tile[c][r]);
    }
}

// ---------------- K1: weights = softmax(x @ Ws + bs) ---------------------------
// 64-row tiles, dbuf LDS, ONE barrier/stage, 2-deep A(x) prefetch.
__global__ __launch_bounds__(256) void k_assign2(
    const float* __restrict__ x, const unsigned short* __restrict__ WsT,
    const float* __restrict__ bs, unsigned short* __restrict__ weights,
    float* __restrict__ wsum)
{
    __shared__ __align__(16) unsigned At32[2][2048];
    __shared__ __align__(16) unsigned Bt32[2][4096];
    __shared__ float wsum_loc[128];

    int t = threadIdx.x;
    int lane = t & 63;
    int wid = t >> 6;
    int l15 = lane & 15, lg = lane >> 4;
    int blk = blockIdx.x;
    int b = blk / NB64;
    int rb = blk % NB64;
    int n0 = rb * 64;
    int nvalid = Nn - n0; if (nvalid > 64) nvalid = 64;
    const float* xb = x + (size_t)b * Nn * Cn;

    if (t < 128) wsum_loc[t] = 0.f;

    int arow = t >> 2, aseg = t & 3;
    bool aok = (arow < nvalid);
    const float4* aptr = (const float4*)(xb + (size_t)(n0 + arow) * Cn) + aseg * 4;
    int brow = t >> 2, bseg = t & 3;
    const unsigned short* bp0 = WsT + (size_t)brow * Cn + bseg * 16;
    const unsigned short* bp1 = WsT + (size_t)(brow + 64) * Cn + bseg * 16;

    const f32x4 fz = {0.f, 0.f, 0.f, 0.f};
    f32x4 acc[8];
    #pragma unroll
    for (int j = 0; j < 8; j++) acc[j] = fz;

    float4 raA[4], raB[4];           // 2-deep A prefetch
    #pragma unroll
    for (int i = 0; i < 4; i++) { raA[i] = make_float4(0.f,0.f,0.f,0.f); raB[i] = raA[i]; }
    s16x8 rb0a, rb0b, rb1a, rb1b;

    // prologue: A stages 0,1; B stage 0
    if (aok) {
        raA[0] = aptr[0];  raA[1] = aptr[1];  raA[2] = aptr[2];  raA[3] = aptr[3];
        raB[0] = aptr[16]; raB[1] = aptr[17]; raB[2] = aptr[18]; raB[3] = aptr[19];
    }
    rb0a = *(const s16x8*)(bp0);     rb0b = *(const s16x8*)(bp0 + 8);
    rb1a = *(const s16x8*)(bp1);     rb1b = *(const s16x8*)(bp1 + 8);

    #pragma unroll
    for (int ks = 0; ks < 8; ks++) {
        int cur = ks & 1;
        // write prefetched regs -> LDS[cur]
        {
            float4* ra = (ks & 1) ? raB : raA;
            float v[16] = {ra[0].x, ra[0].y, ra[0].z, ra[0].w,
                           ra[1].x, ra[1].y, ra[1].z, ra[1].w,
                           ra[2].x, ra[2].y, ra[2].z, ra[2].w,
                           ra[3].x, ra[3].y, ra[3].z, ra[3].w};
            #pragma unroll
            for (int h = 0; h < 2; h++) {
                uint4 u;
                u.x = (unsigned)f2bf(v[h*8+0]) | (((unsigned)f2bf(v[h*8+1])) << 16);
                u.y = (unsigned)f2bf(v[h*8+2]) | (((unsigned)f2bf(v[h*8+3])) << 16);
                u.z = (unsigned)f2bf(v[h*8+4]) | (((unsigned)f2bf(v[h*8+5])) << 16);
                u.w = (unsigned)f2bf(v[h*8+6]) | (((unsigned)f2bf(v[h*8+7])) << 16);
                *(uint4*)((char*)At32[cur] + lds_off(arow, aseg * 16 + h * 8)) = u;
            }
            *(s16x8*)((char*)Bt32[cur] + lds_off(brow, bseg * 16)) = rb0a;
            *(s16x8*)((char*)Bt32[cur] + lds_off(brow, bseg * 16 + 8)) = rb0b;
            *(s16x8*)((char*)Bt32[cur] + lds_off(brow + 64, bseg * 16)) = rb1a;
            *(s16x8*)((char*)Bt32[cur] + lds_off(brow + 64, bseg * 16 + 8)) = rb1b;
        }
        // issue loads: A for stage ks+2 (into the buffer just consumed), B for ks+1
        if (ks < 6 && aok) {
            float4* ra = (ks & 1) ? raB : raA;
            int kn = ks + 2;
            ra[0] = aptr[kn*16]; ra[1] = aptr[kn*16+1];
            ra[2] = aptr[kn*16+2]; ra[3] = aptr[kn*16+3];
        }
        if (ks < 7) {
            int kn = ks + 1;
            rb0a = *(const s16x8*)(bp0 + kn*64); rb0b = *(const s16x8*)(bp0 + kn*64 + 8);
            rb1a = *(const s16x8*)(bp1 + kn*64); rb1b = *(const s16x8*)(bp1 + kn*64 + 8);
        }
        __syncthreads();     // single barrier/stage (dbuf proof: see journal)
        #pragma unroll
        for (int m = 0; m < 2; m++) {
            s16x8 af = *(const s16x8*)((const char*)At32[cur] +
                       lds_off(wid * 16 + l15, m * 32 + lg * 8));
            #pragma unroll
            for (int j = 0; j < 8; j++) {
                s16x8 bf = *(const s16x8*)((const char*)Bt32[cur] +
                           lds_off(j * 16 + l15, m * 32 + lg * 8));
                acc[j] = __builtin_amdgcn_mfma_f32_16x16x32_bf16(af, bf, acc[j], 0, 0, 0);
            }
        }
    }
    __syncthreads();   // drain last MFMA reads before wt overlays At32[0..1]

    float bsv[8];
    #pragma unroll
    for (int j = 0; j < 8; j++) bsv[j] = bs[j * 16 + l15];

    unsigned short* wb = weights + (size_t)b * Nn * Sn;
    unsigned short* wt = (unsigned short*)&At32[0][0];   // 16 KB = 64 x 128 bf16
    float wacc[8] = {0.f,0.f,0.f,0.f,0.f,0.f,0.f,0.f};
    #pragma unroll
    for (int r = 0; r < 4; r++) {
        float lv[8];
        #pragma unroll
        for (int j = 0; j < 8; j++) lv[j] = acc[j][r] + bsv[j];
        float m = lv[0];
        #pragma unroll
        for (int j = 1; j < 8; j++) m = fmaxf(m, lv[j]);
        m = fmaxf(m, __shfl_xor(m, 1));
        m = fmaxf(m, __shfl_xor(m, 2));
        m = fmaxf(m, __shfl_xor(m, 4));
        m = fmaxf(m, __shfl_xor(m, 8));
        float e[8], sm = 0.f;
        #pragma unroll
        for (int j = 0; j < 8; j++) { e[j] = __expf(lv[j] - m); sm += e[j]; }
        sm += __shfl_xor(sm, 1);
        sm += __shfl_xor(sm, 2);
        sm += __shfl_xor(sm, 4);
        sm += __shfl_xor(sm, 8);
        float inv = 1.f / sm;
        int rloc = wid * 16 + lg * 4 + r;
        bool valid = (n0 + rloc < Nn);
        #pragma unroll
        for (int j = 0; j < 8; j++) {
            float w = e[j] * inv;
            wt[rloc * 128 + j * 16 + l15] = f2bf(w);
            if (valid) wacc[j] += w;
        }
    }
    #pragma unroll
    for (int j = 0; j < 8; j++) {
        wacc[j] += __shfl_xor(wacc[j], 16);
        wacc[j] += __shfl_xor(wacc[j], 32);
    }
    if (lg == 0) {
        #pragma unroll
        for (int j = 0; j < 8; j++) atomicAdd(&wsum_loc[j * 16 + l15], wacc[j]);
    }
    __syncthreads();
    {
        int orow = t >> 2, oseg = t & 3;
        if (orow < nvalid) {
            uint4* dst = (uint4*)(wb + (size_t)(n0 + orow) * Sn + oseg * 32);
            const uint4* src = (const uint4*)(wt + (size_t)orow * 128 + oseg * 32);
            dst[0] = src[0]; dst[1] = src[1]; dst[2] = src[2]; dst[3] = src[3];
        }
    }
    if (t < 128) atomicAdd(&wsum[b * Sn + t], wsum_loc[t]);
}

// ---------------- CSR build: degree histogram ----------------------------------
__global__ __launch_bounds__(256) void k_deg(
    const int* __restrict__ adj, int* __restrict__ deg)
{
    int e = blockIdx.x * 256 + threadIdx.x;
    if (e < En) atomicAdd(&deg[adj[e]], 1);
}

// ---------------- CSR build: two-level scan (A: per-block inclusive) -----------
__global__ __launch_bounds__(1024) void k_scanA(
    const int* __restrict__ deg, int* __restrict__ offs, int* __restrict__ bsum)
{
    __shared__ int wsums[16];
    __shared__ int excl[16];
    int t = threadIdx.x;
    int lane = t & 63;
    int w = t >> 6;
    int base = blockIdx.x * 1024;
    int v = (base + t < Nn) ? deg[base + t] : 0;
    int sv = v;
    #pragma unroll
    for (int d = 1; d < 64; d <<= 1) {
        int u = __shfl_up(sv, d);
        if (lane >= d) sv += u;
    }
    if (lane == 63) wsums[w] = sv;
    __syncthreads();
    if (t < 16) {
        int xv = wsums[t];
        int sw = xv;
        #pragma unroll
        for (int d = 1; d < 16; d <<= 1) {
            int u = __shfl_up(sw, d);
            if (t >= d) sw += u;
        }
        excl[t] = sw - xv;
        if (t == 15) bsum[blockIdx.x] = sw;
    }
    __syncthreads();
    if (base + t < Nn) offs[base + t + 1] = excl[w] + sv;
    if (blockIdx.x == 0 && t == 0) offs[0] = 0;
}

// ---------------- CSR build: two-level scan (B: add block prefixes) ------------
__global__ __launch_bounds__(1024) void k_scanB(
    int* __restrict__ offs, const int* __restrict__ bsum)
{
    __shared__ int pS;
    int t = threadIdx.x;
    int blk = blockIdx.x;
    if (t == 0) {
        int p = 0;
        for (int j = 0; j < blk; j++) p += bsum[j];
        pS = p;
    }
    __syncthreads();
    int base = blk * 1024;
    if (blk > 0 && base + t < Nn) offs[base + t + 1] += pS;
}

// ---------------- CSR build: fill packed (col, val) edge records ---------------
__global__ __launch_bounds__(256) void k_fill(
    const int* __restrict__ adj, const float* __restrict__ vals,
    const int* __restrict__ offs, int* __restrict__ cursor,
    int2* __restrict__ epack)
{
    int e = blockIdx.x * 256 + threadIdx.x;
    if (e < En) {
        int r = adj[e];
        int p = atomicAdd(&cursor[r], 1);
        epack[offs[r] + p] = make_int2(adj[En + e], __float_as_int(vals[e]));
    }
}

// ---------------- K3: gw rows via 8-parallel edges + s16x8 loads ---------------
__global__ __launch_bounds__(128) void k_gather(
    const unsigned short* __restrict__ weights, const int2* __restrict__ epack,
    const int* __restrict__ offs, unsigned short* __restrict__ gwb)
{
    __shared__ float red[2][8][132];
    int r = blockIdx.x;
    int t = threadIdx.x;
    int eg = t >> 4;
    int sc = t & 15;
    int o0 = offs[r], o1 = offs[r + 1];
    const unsigned short* w0 = weights;
    const unsigned short* w1 = weights + (size_t)Nn * Sn;
    float a0[8], a1[8];
    #pragma unroll
    for (int i = 0; i < 8; i++) { a0[i] = 0.f; a1[i] = 0.f; }
    for (int j = o0 + eg; j < o1; j += 8) {
        int2 e = epack[j];
        float v = __int_as_float(e.y);
        s16x8 x0 = *(const s16x8*)(w0 + (size_t)e.x * Sn + sc * 8);
        s16x8 x1 = *(const s16x8*)(w1 + (size_t)e.x * Sn + sc * 8);
        #pragma unroll
        for (int i = 0; i < 8; i++) {
            a0[i] += v * bf2f((unsigned short)x0[i]);
            a1[i] += v * bf2f((unsigned short)x1[i]);
        }
    }
    #pragma unroll
    for (int i = 0; i < 8; i++) {
        red[0][eg][sc * 8 + i] = a0[i];
        red[1][eg][sc * 8 + i] = a1[i];
    }
    __syncthreads();
    float s0 = 0.f, s1 = 0.f;
    #pragma unroll
    for (int gix = 0; gix < 8; gix++) { s0 += red[0][gix][t]; s1 += red[1][gix][t]; }
    gwb[(size_t)r * Sn + t] = f2bf(s0);
    gwb[(size_t)Nn * Sn + (size_t)r * Sn + t] = f2bf(s1);
}

// ---------------- K2: slices partials, pipelined, single barrier ---------------
__global__ __launch_bounds__(256) void k_mmS(
    const unsigned short* __restrict__ wAall, const float* __restrict__ xall,
    float* __restrict__ partial)
{
    __shared__ __align__(16) unsigned At32[2][4096];
    __shared__ __align__(16) unsigned Bt32[2][4096];
    int t = threadIdx.x;
    int lane = t & 63;
    int wid = t >> 6;
    int ws = wid & 1, wc = wid >> 1;
    int blk = blockIdx.x;
    int b = blk / (4 * S_KB);
    int rem = blk % (4 * S_KB);
    int cb = rem / S_KB;
    int kb = rem % S_KB;
    int n0 = kb * S_CHUNK;
    int c0 = cb * 128;
    const unsigned short* wA = wAall + (size_t)b * Nn * Sn;
    const float* Bsrc = xall + (size_t)b * Nn * Cn;

    f32x4 acc[4][4];
    const f32x4 fz = {0.f, 0.f, 0.f, 0.f};
    #pragma unroll
    for (int i = 0; i < 4; i++) {
        #pragma unroll
        for (int j = 0; j < 4; j++) acc[i][j] = fz;
    }

    int l15 = lane & 15, lg = lane >> 4;
    int c = t & 15;
    int p0 = t >> 4;

    s16x8 pa[2][2];
    float4 pb[2][4];
    const s16x8 z8 = {0,0,0,0,0,0,0,0};

    auto LOADS = [&](int kt) {
        #pragma unroll
        for (int h = 0; h < 2; h++) {
            int nl = 2 * (p0 + h * 16);
            int ng = n0 + kt + nl;
            pa[h][0] = z8; pa[h][1] = z8;
            pb[h][0] = make_float4(0.f,0.f,0.f,0.f); pb[h][1] = pb[h][0];
            pb[h][2] = pb[h][0]; pb[h][3] = pb[h][0];
            if (ng < Nn) {
                pa[h][0] = *(const s16x8*)(wA + (size_t)ng * Sn + 8 * c);
                pb[h][0] = *(const float4*)(Bsrc + (size_t)ng * Cn + c0 + 8 * c);
                pb[h][1] = *(const float4*)(Bsrc + (size_t)ng * Cn + c0 + 8 * c + 4);
            }
            if (ng + 1 < Nn) {
                pa[h][1] = *(const s16x8*)(wA + (size_t)(ng + 1) * Sn + 8 * c);
                pb[h][2] = *(const float4*)(Bsrc + (size_t)(ng + 1) * Cn + c0 + 8 * c);
                pb[h][3] = *(const float4*)(Bsrc + (size_t)(ng + 1) * Cn + c0 + 8 * c + 4);
            }
        }
    };
    auto STORE = [&](int buf) {
        #pragma unroll
        for (int h = 0; h < 2; h++) {
            int nl = 2 * (p0 + h * 16);
            #pragma unroll
            for (int i = 0; i < 8; i++) {
                unsigned val = ((unsigned)(unsigned short)pa[h][0][i]) |
                               (((unsigned)(unsigned short)pa[h][1][i]) << 16);
                At32[buf][lds_off(8 * c + i, nl) >> 2] = val;
            }
            float b0[8] = {pb[h][0].x, pb[h][0].y, pb[h][0].z, pb[h][0].w,
                           pb[h][1].x, pb[h][1].y, pb[h][1].z, pb[h][1].w};
            float b1[8] = {pb[h][2].x, pb[h][2].y, pb[h][2].z, pb[h][2].w,
                           pb[h][3].x, pb[h][3].y, pb[h][3].z, pb[h][3].w};
            #pragma unroll
            for (int i = 0; i < 8; i++) {
                unsigned val = (unsigned)f2bf(b0[i]) | (((unsigned)f2bf(b1[i])) << 16);
                Bt32[buf][lds_off(8 * c + i, nl) >> 2] = val;
            }
        }
    };

    LOADS(0);
    #pragma unroll 1
    for (int it = 0; it < 5; it++) {
        int cur = it & 1;
        STORE(cur);
        if (it < 4) LOADS((it + 1) * 64);
        __syncthreads();   // single barrier per stage (dbuf-safe)
        #pragma unroll
        for (int m = 0; m < 2; m++) {
            s16x8 af[4], bfr[4];
            #pragma unroll
            for (int i = 0; i < 4; i++) {
                int row = ws * 64 + i * 16 + l15;
                af[i] = *(const s16x8*)((const char*)At32[cur] + lds_off(row, m * 32 + lg * 8));
            }
            #pragma unroll
            for (int j = 0; j < 4; j++) {
                int row = wc * 64 + j * 16 + l15;
                bfr[j] = *(const s16x8*)((const char*)Bt32[cur] + lds_off(row, m * 32 + lg * 8));
            }
            #pragma unroll
            for (int i = 0; i < 4; i++) {
                #pragma unroll
                for (int j = 0; j < 4; j++)
                    acc[i][j] = __builtin_amdgcn_mfma_f32_16x16x32_bf16(
                        af[i], bfr[j], acc[i][j], 0, 0, 0);
            }
        }
    }

    float* pp = partial + (size_t)blk * 16384;
    #pragma unroll
    for (int i = 0; i < 4; i++) {
        int srow = ws * 64 + i * 16 + lg * 4;
        #pragma unroll
        for (int j = 0; j < 4; j++) {
            int ccol = wc * 64 + j * 16 + l15;
            #pragma unroll
            for (int r = 0; r < 4; r++)
                pp[(size_t)(srow + r) * 128 + ccol] = acc[i][j][r];
        }
    }
}

// ---------------- K4: gb partials, pipelined, single barrier -------------------
__global__ __launch_bounds__(256) void k_mmG(
    const unsigned short* __restrict__ wAall, const unsigned short* __restrict__ gwall,
    float* __restrict__ partial)
{
    __shared__ __align__(16) unsigned At32[2][4096];
    __shared__ __align__(16) unsigned Bt32[2][4096];
    int t = threadIdx.x;
    int lane = t & 63;
    int wid = t >> 6;
    int ws = wid & 1, wc = wid >> 1;
    int blk = blockIdx.x;
    int b = blk / G_KB;
    int kb = blk % G_KB;
    int n0 = kb * G_CHUNK;
    const unsigned short* wA = wAall + (size_t)b * Nn * Sn;
    const unsigned short* Bsrc = gwall + (size_t)b * Nn * Sn;

    f32x4 acc[4][4];
    const f32x4 fz = {0.f, 0.f, 0.f, 0.f};
    #pragma unroll
    for (int i = 0; i < 4; i++) {
        #pragma unroll
        for (int j = 0; j < 4; j++) acc[i][j] = fz;
    }

    int l15 = lane & 15, lg = lane >> 4;
    int c = t & 15;
    int p0 = t >> 4;

    s16x8 pa[2][2], pg[2][2];
    const s16x8 z8 = {0,0,0,0,0,0,0,0};

    auto LOADS = [&](int kt) {
        #pragma unroll
        for (int h = 0; h < 2; h++) {
            int nl = 2 * (p0 + h * 16);
            int ng = n0 + kt + nl;
            pa[h][0] = z8; pa[h][1] = z8; pg[h][0] = z8; pg[h][1] = z8;
            if (ng < Nn) {
                pa[h][0] = *(const s16x8*)(wA + (size_t)ng * Sn + 8 * c);
                pg[h][0] = *(const s16x8*)(Bsrc + (size_t)ng * Sn + 8 * c);
            }
            if (ng + 1 < Nn) {
                pa[h][1] = *(const s16x8*)(wA + (size_t)(ng + 1) * Sn + 8 * c);
                pg[h][1] = *(const s16x8*)(Bsrc + (size_t)(ng + 1) * Sn + 8 * c);
            }
        }
    };
    auto STORE = [&](int buf) {
        #pragma unroll
        for (int h = 0; h < 2; h++) {
            int nl = 2 * (p0 + h * 16);
            #pragma unroll
            for (int i = 0; i < 8; i++) {
                unsigned va = ((unsigned)(unsigned short)pa[h][0][i]) |
                              (((unsigned)(unsigned short)pa[h][1][i]) << 16);
                At32[buf][lds_off(8 * c + i, nl) >> 2] = va;
                unsigned vg = ((unsigned)(unsigned short)pg[h][0][i]) |
                              (((unsigned)(unsigned short)pg[h][1][i]) << 16);
                Bt32[buf][lds_off(8 * c + i, nl) >> 2] = vg;
            }
        }
    };

    LOADS(0);
    #pragma unroll 1
    for (int it = 0; it < 2; it++) {
        int cur = it & 1;
        STORE(cur);
        if (it < 1) LOADS(64);
        __syncthreads();
        #pragma unroll
        for (int m = 0; m < 2; m++) {
            s16x8 af[4], bfr[4];
            #pragma unroll
            for (int i = 0; i < 4; i++) {
                int row = ws * 64 + i * 16 + l15;
                af[i] = *(const s16x8*)((const char*)At32[cur] + lds_off(row, m * 32 + lg * 8));
            }
            #pragma unroll
            for (int j = 0; j < 4; j++) {
                int row = wc * 64 + j * 16 + l15;
                bfr[j] = *(const s16x8*)((const char*)Bt32[cur] + lds_off(row, m * 32 + lg * 8));
            }
            #pragma unroll
            for (int i = 0; i < 4; i++) {
                #pragma unroll
                for (int j = 0; j < 4; j++)
                    acc[i][j] = __builtin_amdgcn_mfma_f32_16x16x32_bf16(
                        af[i], bfr[j], acc[i][j], 0, 0, 0);
            }
        }
    }

    float* pp = partial + (size_t)blk * 16384;
    #pragma unroll
    for (int i = 0; i < 4; i++) {
        int srow = ws * 64 + i * 16 + lg * 4;
        #pragma unroll
        for (int j = 0; j < 4; j++) {
            int ccol = wc * 64 + j * 16 + l15;
            #pragma unroll
            for (int r = 0; r < 4; r++)
                pp[(size_t)(srow + r) * 128 + ccol] = acc[i][j][r];
        }
    }
}

// ---------------- fused reduce: partialS -> sl16, partialG -> gb_raw -----------
__global__ __launch_bounds__(256) void k_reduceSG(
    const float* __restrict__ pS, const float* __restrict__ pG,
    const float* __restrict__ wsum, unsigned short* __restrict__ sl16,
    float* __restrict__ gb_raw)
{
    int g = blockIdx.x * 256 + threadIdx.x;
    if (g < Bn * Sn * Cn) {
        int c = g & 127;
        int s = (g >> 7) & 127;
        int cb = (g >> 14) & 3;
        int b = g >> 16;
        const float* pp = pS + (size_t)(b * 4 + cb) * S_KB * 16384 + (size_t)s * 128 + c;
        float sum = 0.f;
        #pragma unroll 7
        for (int kb = 0; kb < S_KB; kb++) sum += pp[(size_t)kb * 16384];
        sl16[((size_t)b * Sn + s) * Cn + cb * 128 + c] =
            f2bf(sum / fmaxf(wsum[b * Sn + s], EPSf));
    } else {
        int g2 = g - Bn * Sn * Cn;
        int t2 = g2 & 127;
        int s = (g2 >> 7) & 127;
        int b = g2 >> 14;
        const float* pp = pG + (size_t)b * G_KB * 16384 + (size_t)s * 128 + t2;
        float sum = 0.f;
        #pragma unroll 8
        for (int kb = 0; kb < G_KB; kb++) sum += pp[(size_t)kb * 16384];
        gb_raw[(size_t)b * 16384 + (size_t)s * 128 + t2] = sum;
    }
}

// ---------------- K4b: symmetrize, row-normalize, log --------------------------
__global__ __launch_bounds__(128) void k_gb_fin(
    const float* __restrict__ gb_raw, float* __restrict__ gb)
{
    int bid = blockIdx.x;
    int b = bid >> 7, i = bid & 127;
    int j = threadIdx.x;
    const float* gr = gb_raw + (size_t)b * Sn * Sn;
    float sym = 0.5f * (gr[i * Sn + j] + gr[j * Sn + i]);
    float sum = sym;
    #pragma unroll
    for (int d = 1; d < 64; d <<= 1) sum += __shfl_xor(sum, d);
    __shared__ float wred[2];
    if ((j & 63) == 0) wred[j >> 6] = sum;
    __syncthreads();
    sum = wred[0] + wred[1];
    float r = fmaxf(sum, EPSf);
    gb[(size_t)b * Sn * Sn + (size_t)i * Sn + j] = logf(fmaxf(sym / r, EPSf));
}

// ---------------- K5: q/k/v = sl16 @ WT[z] + bias, MFMA, fused -----------------
__global__ __launch_bounds__(256) void k_qkv(
    const unsigned short* __restrict__ sl16, const unsigned short* __restrict__ WT,
    const float* __restrict__ bq, const float* __restrict__ bk,
    const float* __restrict__ bv,
    float* __restrict__ q, float* __restrict__ kb, float* __restrict__ vb)
{
    __shared__ __align__(16) unsigned At32[4096];
    __shared__ __align__(16) unsigned Bt32[4096];
    int t = threadIdx.x;
    int lane = t & 63;
    int wid = t >> 6;
    int ws = wid & 1, wc = wid >> 1;
    int l15 = lane & 15, lg = lane >> 4;
    int rb = blockIdx.x, cb = blockIdx.y, sel = blockIdx.z;
    const unsigned short* Bmat = WT + (size_t)sel * Cn * Cn;
    const float* bias = (sel == 0) ? bq : (sel == 1) ? bk : bv;
    float* outp = (sel == 0) ? q : (sel == 1) ? kb : vb;

    f32x4 acc[4][4];
    const f32x4 fz = {0.f, 0.f, 0.f, 0.f};
    #pragma unroll
    for (int i = 0; i < 4; i++) {
        #pragma unroll
        for (int j = 0; j < 4; j++) acc[i][j] = fz;
    }

    for (int ks = 0; ks < 8; ks++) {
        stage_bf16tile(sl16 + (size_t)rb * 128 * Cn + ks * 64, Cn, 128, At32, t);
        stage_bf16tile(Bmat + (size_t)cb * 128 * Cn + ks * 64, Cn, 128, Bt32, t);
        __syncthreads();
        #pragma unroll
        for (int m = 0; m < 2; m++) {
            s16x8 af[4], bfr[4];
            #pragma unroll
            for (int i = 0; i < 4; i++)
                af[i] = *(const s16x8*)((const char*)At32 +
                        lds_off(ws * 64 + i * 16 + l15, m * 32 + lg * 8));
            #pragma unroll
            for (int j = 0; j < 4; j++)
                bfr[j] = *(const s16x8*)((const char*)Bt32 +
                        lds_off(wc * 64 + j * 16 + l15, m * 32 + lg * 8));
            #pragma unroll
            for (int i = 0; i < 4; i++) {
                #pragma unroll
                for (int j = 0; j < 4; j++)
                    acc[i][j] = __builtin_amdgcn_mfma_f32_16x16x32_bf16(
                        af[i], bfr[j], acc[i][j], 0, 0, 0);
            }
        }
        __syncthreads();
    }

    float bvv[4];
    #pragma unroll
    for (int j = 0; j < 4; j++) bvv[j] = bias[cb * 128 + wc * 64 + j * 16 + l15];
    #pragma unroll
    for (int i = 0; i < 4; i++) {
        #pragma unroll
        for (int r = 0; r < 4; r++) {
            int m = rb * 128 + ws * 64 + i * 16 + lg * 4 + r;
            #pragma unroll
            for (int j = 0; j < 4; j++)
                outp[(size_t)m * Cn + cb * 128 + wc * 64 + j * 16 + l15] =
                    acc[i][j][r] + bvv[j];
        }
    }
}

// ---------------- K6: attention per (b,h,i) -> bf16 out ------------------------
__global__ __launch_bounds__(128) void k_attn(
    const float* __restrict__ q, const float* __restrict__ k,
    const float* __restrict__ v, const float* __restrict__ gb,
    const float* __restrict__ beta_raw, unsigned short* __restrict__ attn16)
{
    __shared__ float kv[128][65];
    __shared__ float qv[64];
    __shared__ float p[128];
    __shared__ float wred[2][2];

    int t = threadIdx.x;
    int bid = blockIdx.x;
    int b = bid / (Hn * Sn);
    int h = (bid / Sn) % Hn;
    int i = bid % Sn;
    size_t base = (size_t)b * Sn * Cn + (size_t)h * Dn;

    if (t < 64) qv[t] = q[base + (size_t)i * Cn + t];
    for (int l = 0; l < 64; l++) {
        int idx = t + l * 128;
        int j = idx >> 6, d = idx & 63;
        kv[j][d] = k[base + (size_t)j * Cn + d];
    }
    __syncthreads();

    float dot = 0.f;
    #pragma unroll
    for (int d = 0; d < 64; d++) dot += qv[d] * kv[t][d];

    float beta = log1pf(__expf(beta_raw[0]));
    float logit = dot * 0.125f + beta * gb[(size_t)b * Sn * Sn + (size_t)i * Sn + t];

    float m = logit;
    #pragma unroll
    for (int d = 1; d < 64; d <<= 1) m = fmaxf(m, __shfl_xor(m, d));
    if ((t & 63) == 0) wred[0][t >> 6] = m;
    __syncthreads();
    m = fmaxf(wred[0][0], wred[0][1]);
    float e = __expf(logit - m);
    float sm = e;
    #pragma unroll
    for (int d = 1; d < 64; d <<= 1) sm += __shfl_xor(sm, d);
    if ((t & 63) == 0) wred[1][t >> 6] = sm;
    __syncthreads();
    sm = wred[1][0] + wred[1][1];
    p[t] = e / sm;
    __syncthreads();

    for (int l = 0; l < 64; l++) {
        int idx = t + l * 128;
        int j = idx >> 6, d = idx & 63;
        kv[j][d] = v[base + (size_t)j * Cn + d];
    }
    __syncthreads();

    if (t < 64) {
        float o = 0.f;
        #pragma unroll 8
        for (int j = 0; j < 128; j++) o += p[j] * kv[j][t];
        attn16[base + (size_t)i * Cn + t] = f2bf(o);
    }
}

// ---------------- K7: SoT[b][c][s] = (attn16 @ WoT + bo)^T bf16 ----------------
__global__ __launch_bounds__(256) void k_wo(
    const unsigned short* __restrict__ attn16, const unsigned short* __restrict__ WoT,
    const float* __restrict__ bo, unsigned short* __restrict__ SoT)
{
    __shared__ __align__(16) unsigned At32[4096];
    __shared__ __align__(16) unsigned Bt32[4096];
    int t = threadIdx.x;
    int lane = t & 63;
    int wid = t >> 6;
    int ws = wid & 1, wc = wid >> 1;
    int l15 = lane & 15, lg = lane >> 4;
    int b = blockIdx.x, cb = blockIdx.y;

    f32x4 acc[4][4];
    const f32x4 fz = {0.f, 0.f, 0.f, 0.f};
    #pragma unroll
    for (int i = 0; i < 4; i++) {
        #pragma unroll
        for (int j = 0; j < 4; j++) acc[i][j] = fz;
    }

    for (int ks = 0; ks < 8; ks++) {
        stage_bf16tile(attn16 + (size_t)b * 128 * Cn + ks * 64, Cn, 128, At32, t);
        stage_bf16tile(WoT + (size_t)cb * 128 * Cn + ks * 64, Cn, 128, Bt32, t);
        __syncthreads();
        #pragma unroll
        for (int m = 0; m < 2; m++) {
            s16x8 af[4], bfr[4];
            #pragma unroll
            for (int i = 0; i < 4; i++)
                af[i] = *(const s16x8*)((const char*)At32 +
                        lds_off(ws * 64 + i * 16 + l15, m * 32 + lg * 8));
            #pragma unroll
            for (int j = 0; j < 4; j++)
                bfr[j] = *(const s16x8*)((const char*)Bt32 +
                        lds_off(wc * 64 + j * 16 + l15, m * 32 + lg * 8));
            #pragma unroll
            for (int i = 0; i < 4; i++) {
                #pragma unroll
                for (int j = 0; j < 4; j++)
                    acc[i][j] = __builtin_amdgcn_mfma_f32_16x16x32_bf16(
                        af[i], bfr[j], acc[i][j], 0, 0, 0);
            }
        }
        __syncthreads();
    }

    float bvv[4];
    #pragma unroll
    for (int j = 0; j < 4; j++) bvv[j] = bo[cb * 128 + wc * 64 + j * 16 + l15];
    unsigned short* sb = SoT + (size_t)b * Cn * Sn;
    #pragma unroll
    for (int i = 0; i < 4; i++) {
        #pragma unroll
        for (int j = 0; j < 4; j++) {
            int c = cb * 128 + wc * 64 + j * 16 + l15;
            #pragma unroll
            for (int r = 0; r < 4; r++) {
                int s = ws * 64 + i * 16 + lg * 4 + r;
                sb[(size_t)c * Sn + s] = f2bf(acc[i][j][r] + bvv[j]);
            }
        }
    }
}

// ---------------- K8: out[n][c] = sum_s w[n,s]*so[s,c] via MFMA ----------------
__global__ __launch_bounds__(256) void k_out2(
    const unsigned short* __restrict__ wAll, const unsigned short* __restrict__ SoT,
    float* __restrict__ out)
{
    __shared__ __align__(16) unsigned At32[4096];
    __shared__ __align__(16) unsigned Bt32[4096];
    int t = threadIdx.x;
    int lane = t & 63;
    int wid = t >> 6;
    int ws = wid & 1, wc = wid >> 1;
    int l15 = lane & 15, lg = lane >> 4;
    int blk = blockIdx.x;
    int b = blk / (NB128 * 4);
    int rem = blk % (NB128 * 4);
    int rb = rem >> 2;
    int cb = rem & 3;
    int n0 = rb * 128, c0 = cb * 128;
    int nvalid = Nn - n0; if (nvalid > 128) nvalid = 128;
    const unsigned short* wb = wAll + (size_t)b * Nn * Sn;
    const unsigned short* sb = SoT + (size_t)b * Cn * Sn;

    f32x4 acc[4][4];
    const f32x4 fz = {0.f, 0.f, 0.f, 0.f};
    #pragma unroll
    for (int i = 0; i < 4; i++) {
        #pragma unroll
        for (int j = 0; j < 4; j++) acc[i][j] = fz;
    }

    #pragma unroll
    for (int ksi = 0; ksi < 2; ksi++) {
        stage_bf16tile(wb + (size_t)n0 * Sn + ksi * 64, Sn, nvalid, At32, t);
        stage_bf16tile(sb + (size_t)c0 * Sn + ksi * 64, Sn, 128, Bt32, t);
        __syncthreads();
        #pragma unroll
        for (int m = 0; m < 2; m++) {
            s16x8 af[4], bfr[4];
            #pragma unroll
            for (int i = 0; i < 4; i++)
                af[i] = *(const s16x8*)((const char*)At32 +
                        lds_off(ws * 64 + i * 16 + l15, m * 32 + lg * 8));
            #pragma unroll
            for (int j = 0; j < 4; j++)
                bfr[j] = *(const s16x8*)((const char*)Bt32 +
                        lds_off(wc * 64 + j * 16 + l15, m * 32 + lg * 8));
            #pragma unroll
            for (int i = 0; i < 4; i++) {
                #pragma unroll
                for (int j = 0; j < 4; j++)
                    acc[i][j] = __builtin_amdgcn_mfma_f32_16x16x32_bf16(
                        af[i], bfr[j], acc[i][j], 0, 0, 0);
            }
        }
        __syncthreads();
    }

    #pragma unroll
    for (int i = 0; i < 4; i++) {
        #pragma unroll
        for (int r = 0; r < 4; r++) {
            int n = n0 + ws * 64 + i * 16 + lg * 4 + r;
            if (n < Nn) {
                #pragma unroll
                for (int j = 0; j < 4; j++)
                    out[((size_t)b * Nn + n) * Cn + c0 + wc * 64 + j * 16 + l15] =
                        acc[i][j][r];
            }
        }
    }
}

extern "C" void kernel_launch(void* const* d_in, const int* in_sizes, int n_in,
                              void* d_out, int out_size, void* d_ws, size_t ws_size,
                              hipStream_t stream)
{
    const float* x  = (const float*)d_in[0];
    const int* adj  = (const int*)d_in[1];
    const float* av = (const float*)d_in[2];
    const float* Ws = (const float*)d_in[3];
    const float* bs = (const float*)d_in[4];
    const float* Wq = (const float*)d_in[5];
    const float* bq = (const float*)d_in[6];
    const float* Wk = (const float*)d_in[7];
    const float* bk = (const float*)d_in[8];
    const float* Wv = (const float*)d_in[9];
    const float* bv = (const float*)d_in[10];
    const float* Wo = (const float*)d_in[11];
    const float* bo = (const float*)d_in[12];
    const float* br = (const float*)d_in[13];
    float* out = (float*)d_out;
    (void)in_sizes; (void)n_in; (void)out_size; (void)ws_size;

    char* ws = (char*)d_ws;
    size_t off = 0;
    unsigned short* wb16  = (unsigned short*)(ws + off); off += (size_t)Bn * Nn * Sn * 2;
    unsigned short* gwb16 = (unsigned short*)(ws + off); off += (size_t)Bn * Nn * Sn * 2;
    unsigned short* sl16  = (unsigned short*)(ws + off); off += (size_t)Bn * Sn * Cn * 2;
    float* wsum       = (float*)(ws + off); off += 1024;
    float* gb_raw     = (float*)(ws + off); off += (size_t)Bn * Sn * Sn * 4;
    float* gb         = (float*)(ws + off); off += (size_t)Bn * Sn * Sn * 4;
    float* q          = (float*)(ws + off); off += (size_t)Bn * Sn * Cn * 4;
    float* kbuf       = (float*)(ws + off); off += (size_t)Bn * Sn * Cn * 4;
    float* vbuf       = (float*)(ws + off); off += (size_t)Bn * Sn * Cn * 4;
    unsigned short* attn16 = (unsigned short*)(ws + off); off += (size_t)Bn * Sn * Cn * 2;
    unsigned short* WsT = (unsigned short*)(ws + off); off += (size_t)Sn * Cn * 2;
    unsigned short* WT  = (unsigned short*)(ws + off); off += (size_t)4 * Cn * Cn * 2;
    unsigned short* SoT = (unsigned short*)(ws + off); off += (size_t)Bn * Cn * Sn * 2;
    char* U = ws + off;
    int*  deg    = (int*)(U);
    int*  cursor = (int*)(U + 80128);
    int*  offs   = (int*)(U + 160256);
    int2* epack  = (int2*)(U + 240640);
    int*  bsum   = (int*)(U + 2800640);
    float* partialS = (float*)U;
    float* partialG = (float*)(U + (size_t)504 * 65536);

    k_prepW<<<dim3(16, 16, 5), 256, 0, stream>>>(Ws, Wq, Wk, Wv, Wo, WsT, WT,
                                                 (int*)U, wsum);
    k_assign2<<<Bn * NB64, 256, 0, stream>>>(x, WsT, bs, wb16, wsum);

    k_deg<<<(En + 255) / 256, 256, 0, stream>>>(adj, deg);
    k_scanA<<<NSCAN, 1024, 0, stream>>>(deg, offs, bsum);
    k_scanB<<<NSCAN, 1024, 0, stream>>>(offs, bsum);
    k_fill<<<(En + 255) / 256, 256, 0, stream>>>(adj, av, offs, cursor, epack);
    k_gather<<<Nn, 128, 0, stream>>>(wb16, epack, offs, gwb16);

    k_mmS<<<Bn * 4 * S_KB, 256, 0, stream>>>(wb16, x, partialS);
    k_mmG<<<Bn * G_KB, 256, 0, stream>>>(wb16, gwb16, partialG);
    k_reduceSG<<<(Bn * Sn * Cn + Bn * Sn * Sn) / 256, 256, 0, stream>>>(
        partialS, partialG, wsum, sl16, gb_raw);
    k_gb_fin<<<Bn * Sn, 128, 0, stream>>>(gb_raw, gb);

    k_qkv<<<dim3(2, 4, 3), 256, 0, stream>>>(sl16, WT, bq, bk, bv, q, kbuf, vbuf);
    k_attn<<<Bn * Hn * Sn, 128, 0, stream>>>(q, kbuf, vbuf, gb, br, attn16);
    k_wo<<<dim3(2, 4), 256, 0, stream>>>(attn16, WT + (size_t)3 * Cn * Cn, bo, SoT);

    k_out2<<<Bn * NB128 * 4, 256, 0, stream>>>(wb16, SoT, out);
}

// Round 13
// 225.344 us; speedup vs baseline: 1.0219x; 1.0219x over previous
//
#include <hip/hip_runtime.h>
#include <math.h>

#define Bn 2
#define Nn 20000
#define Cn 512
#define Sn 128
#define Hn 8
#define Dn 64
#define En 320000
#define EPSf 1e-6f
#define NB64 313   // ceil(20000/64)
#define NB128 157  // ceil(20000/128)
#define NSCAN 20   // ceil(20000/1024)

#define S_CHUNK 320
#define S_KB 63        // 63*320 = 20160 >= 20000
#define G_CHUNK 128
#define G_KB 157       // 157*128 = 20096 >= 20000

typedef __attribute__((ext_vector_type(4))) float f32x4;
typedef __attribute__((ext_vector_type(8))) short s16x8;

__device__ __forceinline__ unsigned short f2bf(float f) {
    unsigned u = __float_as_uint(f);
    return (unsigned short)((u + 0x7fffu + ((u >> 16) & 1u)) >> 16);
}
__device__ __forceinline__ float bf2f(unsigned short h) {
    return __uint_as_float(((unsigned)h) << 16);
}

// Swizzled LDS byte offset for a [rows][64 k] bf16 tile (rows<=128).
__device__ __forceinline__ unsigned lds_off(int row, int n) {
    unsigned ch = ((((unsigned)n >> 3) ^ ((unsigned)row & 7u) ^ (((unsigned)row >> 3) & 7u)) & 7u);
    return (unsigned)row * 128u + ch * 16u + ((unsigned)n & 7u) * 2u;
}

// ---- stage [128 rows][64 k] bf16 tile from bf16 row-major source --------------
__device__ __forceinline__ void stage_bf16tile(
    const unsigned short* __restrict__ src, int stride, int nvalid, unsigned* dst, int t)
{
    #pragma unroll
    for (int l = 0; l < 2; l++) {
        int task = t + l * 256;
        int row = task >> 2, seg = task & 3;
        s16x8 a = {0,0,0,0,0,0,0,0}, b = {0,0,0,0,0,0,0,0};
        if (row < nvalid) {
            a = *(const s16x8*)(src + (size_t)row * stride + seg * 16);
            b = *(const s16x8*)(src + (size_t)row * stride + seg * 16 + 8);
        }
        *(s16x8*)((char*)dst + lds_off(row, seg * 16)) = a;
        *(s16x8*)((char*)dst + lds_off(row, seg * 16 + 8)) = b;
    }
}

// ---------------- prep: weight transposes + workspace zeroing ------------------
__global__ __launch_bounds__(256) void k_prepW(
    const float* __restrict__ Ws, const float* __restrict__ Wq,
    const float* __restrict__ Wk, const float* __restrict__ Wv,
    const float* __restrict__ Wo, unsigned short* __restrict__ WsT,
    unsigned short* __restrict__ WT, int* __restrict__ zeroU,
    float* __restrict__ wsum)
{
    __shared__ float tile[32][33];
    int t = threadIdx.x;
    int z = blockIdx.z;
    int k0 = blockIdx.x * 32;
    int c0 = blockIdx.y * 32;
    const float* W;
    unsigned short* dst;
    int ncols;
    if (z == 0) {
        if (c0 >= Sn) {
            int idx = (((int)blockIdx.y - 4) * 16 + (int)blockIdx.x) * 256 + t;
            if (idx < 40064) zeroU[idx] = 0;                 // deg + cursor
            else if (idx < 40064 + Bn * Sn) wsum[idx - 40064] = 0.f;
            return;
        }
        W = Ws; dst = WsT; ncols = Sn;
    } else {
        W = (z == 1) ? Wq : (z == 2) ? Wk : (z == 3) ? Wv : Wo;
        dst = WT + (size_t)(z - 1) * Cn * Cn; ncols = Cn;
    }
    #pragma unroll
    for (int l = 0; l < 4; l++) {
        int idx = t + l * 256;
        int r = idx >> 5, c = idx & 31;
        tile[r][c] = W[(size_t)(k0 + r) * ncols + c0 + c];
    }
    __syncthreads();
    #pragma unroll
    for (int l = 0; l < 4; l++) {
        int idx = t + l * 256;
        int r = idx >> 5, c = idx & 31;
        dst[(size_t)(c0 + r) * Cn + k0 + c] = f2bf(tile[c][r]);
    }
}

// ---------------- K1: weights = softmax(x @ Ws + bs) ---------------------------
// A-operand DIRECT global->reg->MFMA (no LDS, no barrier dependency, 2-deep pf).
// B (WsT, L2-hot) via LDS dbuf, single barrier/stage. LDS 32.5KB -> 4 blk/CU.
__global__ __launch_bounds__(256) void k_assign2(
    const float* __restrict__ x, const unsigned short* __restrict__ WsT,
    const float* __restrict__ bs, unsigned short* __restrict__ weights,
    float* __restrict__ wsum)
{
    __shared__ __align__(16) unsigned Bt32[2][4096];   // 2 x 16 KB (128 s x 64 k)
    __shared__ float wsum_loc[128];

    int t = threadIdx.x;
    int lane = t & 63;
    int wid = t >> 6;
    int l15 = lane & 15, lg = lane >> 4;
    int blk = blockIdx.x;
    int b = blk / NB64;
    int rb = blk % NB64;
    int n0 = rb * 64;
    int nvalid = Nn - n0; if (nvalid > 64) nvalid = 64;
    const float* xb = x + (size_t)b * Nn * Cn;

    if (t < 128) wsum_loc[t] = 0.f;

    // A: per-lane direct row pointer (row = n0 + wid*16 + l15)
    int arow = n0 + wid * 16 + l15;
    bool aok = (arow < Nn);
    const float4* aptr = (const float4*)(xb + (size_t)arow * Cn);

    // B staging (cooperative, same as before)
    int brow = t >> 2, bseg = t & 3;
    const unsigned short* bp0 = WsT + (size_t)brow * Cn + bseg * 16;
    const unsigned short* bp1 = WsT + (size_t)(brow + 64) * Cn + bseg * 16;

    const f32x4 fz = {0.f, 0.f, 0.f, 0.f};
    f32x4 acc[8];
    #pragma unroll
    for (int j = 0; j < 8; j++) acc[j] = fz;

    // A prefetch: [stage parity][m][lo/hi], 2-deep
    float4 apf[2][2][2];
    const float4 f4z = make_float4(0.f, 0.f, 0.f, 0.f);
    #pragma unroll
    for (int st = 0; st < 2; st++) {
        #pragma unroll
        for (int m = 0; m < 2; m++) {
            int ci = st * 16 + m * 8 + lg * 2;
            apf[st][m][0] = aok ? aptr[ci]     : f4z;
            apf[st][m][1] = aok ? aptr[ci + 1] : f4z;
        }
    }
    // B prefetch: stage 0
    s16x8 rb0a = *(const s16x8*)(bp0);     s16x8 rb0b = *(const s16x8*)(bp0 + 8);
    s16x8 rb1a = *(const s16x8*)(bp1);     s16x8 rb1b = *(const s16x8*)(bp1 + 8);

    #pragma unroll
    for (int ks = 0; ks < 8; ks++) {
        int cur = ks & 1;
        // consume A(ks) regs -> bf16 fragments BEFORE reloading the slot
        s16x8 afq[2];
        #pragma unroll
        for (int m = 0; m < 2; m++) {
            float4 lo = apf[cur][m][0], hi = apf[cur][m][1];
            s16x8 a;
            a[0] = (short)f2bf(lo.x); a[1] = (short)f2bf(lo.y);
            a[2] = (short)f2bf(lo.z); a[3] = (short)f2bf(lo.w);
            a[4] = (short)f2bf(hi.x); a[5] = (short)f2bf(hi.y);
            a[6] = (short)f2bf(hi.z); a[7] = (short)f2bf(hi.w);
            afq[m] = a;
        }
        // store B prefetch regs -> LDS[cur]
        *(s16x8*)((char*)Bt32[cur] + lds_off(brow, bseg * 16)) = rb0a;
        *(s16x8*)((char*)Bt32[cur] + lds_off(brow, bseg * 16 + 8)) = rb0b;
        *(s16x8*)((char*)Bt32[cur] + lds_off(brow + 64, bseg * 16)) = rb1a;
        *(s16x8*)((char*)Bt32[cur] + lds_off(brow + 64, bseg * 16 + 8)) = rb1b;
        // issue B loads for ks+1
        if (ks < 7) {
            int kn = ks + 1;
            rb0a = *(const s16x8*)(bp0 + kn*64); rb0b = *(const s16x8*)(bp0 + kn*64 + 8);
            rb1a = *(const s16x8*)(bp1 + kn*64); rb1b = *(const s16x8*)(bp1 + kn*64 + 8);
        }
        // issue A loads for ks+2 into the slot just consumed
        if (ks < 6 && aok) {
            int ci = (ks + 2) * 16;
            #pragma unroll
            for (int m = 0; m < 2; m++) {
                apf[cur][m][0] = aptr[ci + m * 8 + lg * 2];
                apf[cur][m][1] = aptr[ci + m * 8 + lg * 2 + 1];
            }
        }
        __syncthreads();     // gates B dbuf only (proof in journal)
        #pragma unroll
        for (int m = 0; m < 2; m++) {
            #pragma unroll
            for (int j = 0; j < 8; j++) {
                s16x8 bf = *(const s16x8*)((const char*)Bt32[cur] +
                           lds_off(j * 16 + l15, m * 32 + lg * 8));
                acc[j] = __builtin_amdgcn_mfma_f32_16x16x32_bf16(afq[m], bf, acc[j], 0, 0, 0);
            }
        }
    }

    float bsv[8];
    #pragma unroll
    for (int j = 0; j < 8; j++) bsv[j] = bs[j * 16 + l15];

    unsigned short* wb = weights + (size_t)b * Nn * Sn;
    unsigned short* wt = (unsigned short*)&Bt32[0][0];   // 16 KB = 64 x 128 bf16
    // safe: after barrier(7), no wave reads Bt32[0] again (stage 7 reads Bt32[1])
    float wacc[8] = {0.f,0.f,0.f,0.f,0.f,0.f,0.f,0.f};
    #pragma unroll
    for (int r = 0; r < 4; r++) {
        float lv[8];
        #pragma unroll
        for (int j = 0; j < 8; j++) lv[j] = acc[j][r] + bsv[j];
        float m = lv[0];
        #pragma unroll
        for (int j = 1; j < 8; j++) m = fmaxf(m, lv[j]);
        m = fmaxf(m, __shfl_xor(m, 1));
        m = fmaxf(m, __shfl_xor(m, 2));
        m = fmaxf(m, __shfl_xor(m, 4));
        m = fmaxf(m, __shfl_xor(m, 8));
        float e[8], sm = 0.f;
        #pragma unroll
        for (int j = 0; j < 8; j++) { e[j] = __expf(lv[j] - m); sm += e[j]; }
        sm += __shfl_xor(sm, 1);
        sm += __shfl_xor(sm, 2);
        sm += __shfl_xor(sm, 4);
        sm += __shfl_xor(sm, 8);
        float inv = 1.f / sm;
        int rloc = wid * 16 + lg * 4 + r;
        bool valid = (n0 + rloc < Nn);
        #pragma unroll
        for (int j = 0; j < 8; j++) {
            float w = e[j] * inv;
            wt[rloc * 128 + j * 16 + l15] = f2bf(w);
            if (valid) wacc[j] += w;
        }
    }
    #pragma unroll
    for (int j = 0; j < 8; j++) {
        wacc[j] += __shfl_xor(wacc[j], 16);
        wacc[j] += __shfl_xor(wacc[j], 32);
    }
    if (lg == 0) {
        #pragma unroll
        for (int j = 0; j < 8; j++) atomicAdd(&wsum_loc[j * 16 + l15], wacc[j]);
    }
    __syncthreads();
    {
        int orow = t >> 2, oseg = t & 3;
        if (orow < nvalid) {
            uint4* dst = (uint4*)(wb + (size_t)(n0 + orow) * Sn + oseg * 32);
            const uint4* src = (const uint4*)(wt + (size_t)orow * 128 + oseg * 32);
            dst[0] = src[0]; dst[1] = src[1]; dst[2] = src[2]; dst[3] = src[3];
        }
    }
    if (t < 128) atomicAdd(&wsum[b * Sn + t], wsum_loc[t]);
}

// ---------------- CSR build: degree histogram ----------------------------------
__global__ __launch_bounds__(256) void k_deg(
    const int* __restrict__ adj, int* __restrict__ deg)
{
    int e = blockIdx.x * 256 + threadIdx.x;
    if (e < En) atomicAdd(&deg[adj[e]], 1);
}

// ---------------- CSR build: two-level scan (A: per-block inclusive) -----------
__global__ __launch_bounds__(1024) void k_scanA(
    const int* __restrict__ deg, int* __restrict__ offs, int* __restrict__ bsum)
{
    __shared__ int wsums[16];
    __shared__ int excl[16];
    int t = threadIdx.x;
    int lane = t & 63;
    int w = t >> 6;
    int base = blockIdx.x * 1024;
    int v = (base + t < Nn) ? deg[base + t] : 0;
    int sv = v;
    #pragma unroll
    for (int d = 1; d < 64; d <<= 1) {
        int u = __shfl_up(sv, d);
        if (lane >= d) sv += u;
    }
    if (lane == 63) wsums[w] = sv;
    __syncthreads();
    if (t < 16) {
        int xv = wsums[t];
        int sw = xv;
        #pragma unroll
        for (int d = 1; d < 16; d <<= 1) {
            int u = __shfl_up(sw, d);
            if (t >= d) sw += u;
        }
        excl[t] = sw - xv;
        if (t == 15) bsum[blockIdx.x] = sw;
    }
    __syncthreads();
    if (base + t < Nn) offs[base + t + 1] = excl[w] + sv;
    if (blockIdx.x == 0 && t == 0) offs[0] = 0;
}

// ---------------- CSR build: two-level scan (B: add block prefixes) ------------
__global__ __launch_bounds__(1024) void k_scanB(
    int* __restrict__ offs, const int* __restrict__ bsum)
{
    __shared__ int pS;
    int t = threadIdx.x;
    int blk = blockIdx.x;
    if (t == 0) {
        int p = 0;
        for (int j = 0; j < blk; j++) p += bsum[j];
        pS = p;
    }
    __syncthreads();
    int base = blk * 1024;
    if (blk > 0 && base + t < Nn) offs[base + t + 1] += pS;
}

// ---------------- CSR build: fill packed (col, val) edge records ---------------
__global__ __launch_bounds__(256) void k_fill(
    const int* __restrict__ adj, const float* __restrict__ vals,
    const int* __restrict__ offs, int* __restrict__ cursor,
    int2* __restrict__ epack)
{
    int e = blockIdx.x * 256 + threadIdx.x;
    if (e < En) {
        int r = adj[e];
        int p = atomicAdd(&cursor[r], 1);
        epack[offs[r] + p] = make_int2(adj[En + e], __float_as_int(vals[e]));
    }
}

// ---------------- K3: gw rows via 8-parallel edges + s16x8 loads ---------------
__global__ __launch_bounds__(128) void k_gather(
    const unsigned short* __restrict__ weights, const int2* __restrict__ epack,
    const int* __restrict__ offs, unsigned short* __restrict__ gwb)
{
    __shared__ float red[2][8][132];
    int r = blockIdx.x;
    int t = threadIdx.x;
    int eg = t >> 4;
    int sc = t & 15;
    int o0 = offs[r], o1 = offs[r + 1];
    const unsigned short* w0 = weights;
    const unsigned short* w1 = weights + (size_t)Nn * Sn;
    float a0[8], a1[8];
    #pragma unroll
    for (int i = 0; i < 8; i++) { a0[i] = 0.f; a1[i] = 0.f; }
    for (int j = o0 + eg; j < o1; j += 8) {
        int2 e = epack[j];
        float v = __int_as_float(e.y);
        s16x8 x0 = *(const s16x8*)(w0 + (size_t)e.x * Sn + sc * 8);
        s16x8 x1 = *(const s16x8*)(w1 + (size_t)e.x * Sn + sc * 8);
        #pragma unroll
        for (int i = 0; i < 8; i++) {
            a0[i] += v * bf2f((unsigned short)x0[i]);
            a1[i] += v * bf2f((unsigned short)x1[i]);
        }
    }
    #pragma unroll
    for (int i = 0; i < 8; i++) {
        red[0][eg][sc * 8 + i] = a0[i];
        red[1][eg][sc * 8 + i] = a1[i];
    }
    __syncthreads();
    float s0 = 0.f, s1 = 0.f;
    #pragma unroll
    for (int gix = 0; gix < 8; gix++) { s0 += red[0][gix][t]; s1 += red[1][gix][t]; }
    gwb[(size_t)r * Sn + t] = f2bf(s0);
    gwb[(size_t)Nn * Sn + (size_t)r * Sn + t] = f2bf(s1);
}

// ---------------- K2: slices partials, pipelined, single barrier ---------------
__global__ __launch_bounds__(256) void k_mmS(
    const unsigned short* __restrict__ wAall, const float* __restrict__ xall,
    float* __restrict__ partial)
{
    __shared__ __align__(16) unsigned At32[2][4096];
    __shared__ __align__(16) unsigned Bt32[2][4096];
    int t = threadIdx.x;
    int lane = t & 63;
    int wid = t >> 6;
    int ws = wid & 1, wc = wid >> 1;
    int blk = blockIdx.x;
    int b = blk / (4 * S_KB);
    int rem = blk % (4 * S_KB);
    int cb = rem / S_KB;
    int kb = rem % S_KB;
    int n0 = kb * S_CHUNK;
    int c0 = cb * 128;
    const unsigned short* wA = wAall + (size_t)b * Nn * Sn;
    const float* Bsrc = xall + (size_t)b * Nn * Cn;

    f32x4 acc[4][4];
    const f32x4 fz = {0.f, 0.f, 0.f, 0.f};
    #pragma unroll
    for (int i = 0; i < 4; i++) {
        #pragma unroll
        for (int j = 0; j < 4; j++) acc[i][j] = fz;
    }

    int l15 = lane & 15, lg = lane >> 4;
    int c = t & 15;
    int p0 = t >> 4;

    s16x8 pa[2][2];
    float4 pb[2][4];
    const s16x8 z8 = {0,0,0,0,0,0,0,0};

    auto LOADS = [&](int kt) {
        #pragma unroll
        for (int h = 0; h < 2; h++) {
            int nl = 2 * (p0 + h * 16);
            int ng = n0 + kt + nl;
            pa[h][0] = z8; pa[h][1] = z8;
            pb[h][0] = make_float4(0.f,0.f,0.f,0.f); pb[h][1] = pb[h][0];
            pb[h][2] = pb[h][0]; pb[h][3] = pb[h][0];
            if (ng < Nn) {
                pa[h][0] = *(const s16x8*)(wA + (size_t)ng * Sn + 8 * c);
                pb[h][0] = *(const float4*)(Bsrc + (size_t)ng * Cn + c0 + 8 * c);
                pb[h][1] = *(const float4*)(Bsrc + (size_t)ng * Cn + c0 + 8 * c + 4);
            }
            if (ng + 1 < Nn) {
                pa[h][1] = *(const s16x8*)(wA + (size_t)(ng + 1) * Sn + 8 * c);
                pb[h][2] = *(const float4*)(Bsrc + (size_t)(ng + 1) * Cn + c0 + 8 * c);
                pb[h][3] = *(const float4*)(Bsrc + (size_t)(ng + 1) * Cn + c0 + 8 * c + 4);
            }
        }
    };
    auto STORE = [&](int buf) {
        #pragma unroll
        for (int h = 0; h < 2; h++) {
            int nl = 2 * (p0 + h * 16);
            #pragma unroll
            for (int i = 0; i < 8; i++) {
                unsigned val = ((unsigned)(unsigned short)pa[h][0][i]) |
                               (((unsigned)(unsigned short)pa[h][1][i]) << 16);
                At32[buf][lds_off(8 * c + i, nl) >> 2] = val;
            }
            float b0[8] = {pb[h][0].x, pb[h][0].y, pb[h][0].z, pb[h][0].w,
                           pb[h][1].x, pb[h][1].y, pb[h][1].z, pb[h][1].w};
            float b1[8] = {pb[h][2].x, pb[h][2].y, pb[h][2].z, pb[h][2].w,
                           pb[h][3].x, pb[h][3].y, pb[h][3].z, pb[h][3].w};
            #pragma unroll
            for (int i = 0; i < 8; i++) {
                unsigned val = (unsigned)f2bf(b0[i]) | (((unsigned)f2bf(b1[i])) << 16);
                Bt32[buf][lds_off(8 * c + i, nl) >> 2] = val;
            }
        }
    };

    LOADS(0);
    #pragma unroll 1
    for (int it = 0; it < 5; it++) {
        int cur = it & 1;
        STORE(cur);
        if (it < 4) LOADS((it + 1) * 64);
        __syncthreads();
        #pragma unroll
        for (int m = 0; m < 2; m++) {
            s16x8 af[4], bfr[4];
            #pragma unroll
            for (int i = 0; i < 4; i++) {
                int row = ws * 64 + i * 16 + l15;
                af[i] = *(const s16x8*)((const char*)At32[cur] + lds_off(row, m * 32 + lg * 8));
            }
            #pragma unroll
            for (int j = 0; j < 4; j++) {
                int row = wc * 64 + j * 16 + l15;
                bfr[j] = *(const s16x8*)((const char*)Bt32[cur] + lds_off(row, m * 32 + lg * 8));
            }
            #pragma unroll
            for (int i = 0; i < 4; i++) {
                #pragma unroll
                for (int j = 0; j < 4; j++)
                    acc[i][j] = __builtin_amdgcn_mfma_f32_16x16x32_bf16(
                        af[i], bfr[j], acc[i][j], 0, 0, 0);
            }
        }
    }

    float* pp = partial + (size_t)blk * 16384;
    #pragma unroll
    for (int i = 0; i < 4; i++) {
        int srow = ws * 64 + i * 16 + lg * 4;
        #pragma unroll
        for (int j = 0; j < 4; j++) {
            int ccol = wc * 64 + j * 16 + l15;
            #pragma unroll
            for (int r = 0; r < 4; r++)
                pp[(size_t)(srow + r) * 128 + ccol] = acc[i][j][r];
        }
    }
}

// ---------------- K4: gb partials, pipelined, single barrier -------------------
__global__ __launch_bounds__(256) void k_mmG(
    const unsigned short* __restrict__ wAall, const unsigned short* __restrict__ gwall,
    float* __restrict__ partial)
{
    __shared__ __align__(16) unsigned At32[2][4096];
    __shared__ __align__(16) unsigned Bt32[2][4096];
    int t = threadIdx.x;
    int lane = t & 63;
    int wid = t >> 6;
    int ws = wid & 1, wc = wid >> 1;
    int blk = blockIdx.x;
    int b = blk / G_KB;
    int kb = blk % G_KB;
    int n0 = kb * G_CHUNK;
    const unsigned short* wA = wAall + (size_t)b * Nn * Sn;
    const unsigned short* Bsrc = gwall + (size_t)b * Nn * Sn;

    f32x4 acc[4][4];
    const f32x4 fz = {0.f, 0.f, 0.f, 0.f};
    #pragma unroll
    for (int i = 0; i < 4; i++) {
        #pragma unroll
        for (int j = 0; j < 4; j++) acc[i][j] = fz;
    }

    int l15 = lane & 15, lg = lane >> 4;
    int c = t & 15;
    int p0 = t >> 4;

    s16x8 pa[2][2], pg[2][2];
    const s16x8 z8 = {0,0,0,0,0,0,0,0};

    auto LOADS = [&](int kt) {
        #pragma unroll
        for (int h = 0; h < 2; h++) {
            int nl = 2 * (p0 + h * 16);
            int ng = n0 + kt + nl;
            pa[h][0] = z8; pa[h][1] = z8; pg[h][0] = z8; pg[h][1] = z8;
            if (ng < Nn) {
                pa[h][0] = *(const s16x8*)(wA + (size_t)ng * Sn + 8 * c);
                pg[h][0] = *(const s16x8*)(Bsrc + (size_t)ng * Sn + 8 * c);
            }
            if (ng + 1 < Nn) {
                pa[h][1] = *(const s16x8*)(wA + (size_t)(ng + 1) * Sn + 8 * c);
                pg[h][1] = *(const s16x8*)(Bsrc + (size_t)(ng + 1) * Sn + 8 * c);
            }
        }
    };
    auto STORE = [&](int buf) {
        #pragma unroll
        for (int h = 0; h < 2; h++) {
            int nl = 2 * (p0 + h * 16);
            #pragma unroll
            for (int i = 0; i < 8; i++) {
                unsigned va = ((unsigned)(unsigned short)pa[h][0][i]) |
                              (((unsigned)(unsigned short)pa[h][1][i]) << 16);
                At32[buf][lds_off(8 * c + i, nl) >> 2] = va;
                unsigned vg = ((unsigned)(unsigned short)pg[h][0][i]) |
                              (((unsigned)(unsigned short)pg[h][1][i]) << 16);
                Bt32[buf][lds_off(8 * c + i, nl) >> 2] = vg;
            }
        }
    };

    LOADS(0);
    #pragma unroll 1
    for (int it = 0; it < 2; it++) {
        int cur = it & 1;
        STORE(cur);
        if (it < 1) LOADS(64);
        __syncthreads();
        #pragma unroll
        for (int m = 0; m < 2; m++) {
            s16x8 af[4], bfr[4];
            #pragma unroll
            for (int i = 0; i < 4; i++) {
                int row = ws * 64 + i * 16 + l15;
                af[i] = *(const s16x8*)((const char*)At32[cur] + lds_off(row, m * 32 + lg * 8));
            }
            #pragma unroll
            for (int j = 0; j < 4; j++) {
                int row = wc * 64 + j * 16 + l15;
                bfr[j] = *(const s16x8*)((const char*)Bt32[cur] + lds_off(row, m * 32 + lg * 8));
            }
            #pragma unroll
            for (int i = 0; i < 4; i++) {
                #pragma unroll
                for (int j = 0; j < 4; j++)
                    acc[i][j] = __builtin_amdgcn_mfma_f32_16x16x32_bf16(
                        af[i], bfr[j], acc[i][j], 0, 0, 0);
            }
        }
    }

    float* pp = partial + (size_t)blk * 16384;
    #pragma unroll
    for (int i = 0; i < 4; i++) {
        int srow = ws * 64 + i * 16 + lg * 4;
        #pragma unroll
        for (int j = 0; j < 4; j++) {
            int ccol = wc * 64 + j * 16 + l15;
            #pragma unroll
            for (int r = 0; r < 4; r++)
                pp[(size_t)(srow + r) * 128 + ccol] = acc[i][j][r];
        }
    }
}

// ---------------- fused reduce: partialS -> sl16, partialG -> gb_raw -----------
__global__ __launch_bounds__(256) void k_reduceSG(
    const float* __restrict__ pS, const float* __restrict__ pG,
    const float* __restrict__ wsum, unsigned short* __restrict__ sl16,
    float* __restrict__ gb_raw)
{
    int g = blockIdx.x * 256 + threadIdx.x;
    if (g < Bn * Sn * Cn) {
        int c = g & 127;
        int s = (g >> 7) & 127;
        int cb = (g >> 14) & 3;
        int b = g >> 16;
        const float* pp = pS + (size_t)(b * 4 + cb) * S_KB * 16384 + (size_t)s * 128 + c;
        float sum = 0.f;
        #pragma unroll 7
        for (int kb = 0; kb < S_KB; kb++) sum += pp[(size_t)kb * 16384];
        sl16[((size_t)b * Sn + s) * Cn + cb * 128 + c] =
            f2bf(sum / fmaxf(wsum[b * Sn + s], EPSf));
    } else {
        int g2 = g - Bn * Sn * Cn;
        int t2 = g2 & 127;
        int s = (g2 >> 7) & 127;
        int b = g2 >> 14;
        const float* pp = pG + (size_t)b * G_KB * 16384 + (size_t)s * 128 + t2;
        float sum = 0.f;
        #pragma unroll 8
        for (int kb = 0; kb < G_KB; kb++) sum += pp[(size_t)kb * 16384];
        gb_raw[(size_t)b * 16384 + (size_t)s * 128 + t2] = sum;
    }
}

// ---------------- K4b: symmetrize, row-normalize, log --------------------------
__global__ __launch_bounds__(128) void k_gb_fin(
    const float* __restrict__ gb_raw, float* __restrict__ gb)
{
    int bid = blockIdx.x;
    int b = bid >> 7, i = bid & 127;
    int j = threadIdx.x;
    const float* gr = gb_raw + (size_t)b * Sn * Sn;
    float sym = 0.5f * (gr[i * Sn + j] + gr[j * Sn + i]);
    float sum = sym;
    #pragma unroll
    for (int d = 1; d < 64; d <<= 1) sum += __shfl_xor(sum, d);
    __shared__ float wred[2];
    if ((j & 63) == 0) wred[j >> 6] = sum;
    __syncthreads();
    sum = wred[0] + wred[1];
    float r = fmaxf(sum, EPSf);
    gb[(size_t)b * Sn * Sn + (size_t)i * Sn + j] = logf(fmaxf(sym / r, EPSf));
}

// ---------------- K5: q/k/v = sl16 @ WT[z] + bias, MFMA, fused -----------------
__global__ __launch_bounds__(256) void k_qkv(
    const unsigned short* __restrict__ sl16, const unsigned short* __restrict__ WT,
    const float* __restrict__ bq, const float* __restrict__ bk,
    const float* __restrict__ bv,
    float* __restrict__ q, float* __restrict__ kb, float* __restrict__ vb)
{
    __shared__ __align__(16) unsigned At32[4096];
    __shared__ __align__(16) unsigned Bt32[4096];
    int t = threadIdx.x;
    int lane = t & 63;
    int wid = t >> 6;
    int ws = wid & 1, wc = wid >> 1;
    int l15 = lane & 15, lg = lane >> 4;
    int rb = blockIdx.x, cb = blockIdx.y, sel = blockIdx.z;
    const unsigned short* Bmat = WT + (size_t)sel * Cn * Cn;
    const float* bias = (sel == 0) ? bq : (sel == 1) ? bk : bv;
    float* outp = (sel == 0) ? q : (sel == 1) ? kb : vb;

    f32x4 acc[4][4];
    const f32x4 fz = {0.f, 0.f, 0.f, 0.f};
    #pragma unroll
    for (int i = 0; i < 4; i++) {
        #pragma unroll
        for (int j = 0; j < 4; j++) acc[i][j] = fz;
    }

    for (int ks = 0; ks < 8; ks++) {
        stage_bf16tile(sl16 + (size_t)rb * 128 * Cn + ks * 64, Cn, 128, At32, t);
        stage_bf16tile(Bmat + (size_t)cb * 128 * Cn + ks * 64, Cn, 128, Bt32, t);
        __syncthreads();
        #pragma unroll
        for (int m = 0; m < 2; m++) {
            s16x8 af[4], bfr[4];
            #pragma unroll
            for (int i = 0; i < 4; i++)
                af[i] = *(const s16x8*)((const char*)At32 +
                        lds_off(ws * 64 + i * 16 + l15, m * 32 + lg * 8));
            #pragma unroll
            for (int j = 0; j < 4; j++)
                bfr[j] = *(const s16x8*)((const char*)Bt32 +
                        lds_off(wc * 64 + j * 16 + l15, m * 32 + lg * 8));
            #pragma unroll
            for (int i = 0; i < 4; i++) {
                #pragma unroll
                for (int j = 0; j < 4; j++)
                    acc[i][j] = __builtin_amdgcn_mfma_f32_16x16x32_bf16(
                        af[i], bfr[j], acc[i][j], 0, 0, 0);
            }
        }
        __syncthreads();
    }

    float bvv[4];
    #pragma unroll
    for (int j = 0; j < 4; j++) bvv[j] = bias[cb * 128 + wc * 64 + j * 16 + l15];
    #pragma unroll
    for (int i = 0; i < 4; i++) {
        #pragma unroll
        for (int r = 0; r < 4; r++) {
            int m = rb * 128 + ws * 64 + i * 16 + lg * 4 + r;
            #pragma unroll
            for (int j = 0; j < 4; j++)
                outp[(size_t)m * Cn + cb * 128 + wc * 64 + j * 16 + l15] =
                    acc[i][j][r] + bvv[j];
        }
    }
}

// ---------------- K6: attention per (b,h,i) -> bf16 out ------------------------
__global__ __launch_bounds__(128) void k_attn(
    const float* __restrict__ q, const float* __restrict__ k,
    const float* __restrict__ v, const float* __restrict__ gb,
    const float* __restrict__ beta_raw, unsigned short* __restrict__ attn16)
{
    __shared__ float kv[128][65];
    __shared__ float qv[64];
    __shared__ float p[128];
    __shared__ float wred[2][2];

    int t = threadIdx.x;
    int bid = blockIdx.x;
    int b = bid / (Hn * Sn);
    int h = (bid / Sn) % Hn;
    int i = bid % Sn;
    size_t base = (size_t)b * Sn * Cn + (size_t)h * Dn;

    if (t < 64) qv[t] = q[base + (size_t)i * Cn + t];
    for (int l = 0; l < 64; l++) {
        int idx = t + l * 128;
        int j = idx >> 6, d = idx & 63;
        kv[j][d] = k[base + (size_t)j * Cn + d];
    }
    __syncthreads();

    float dot = 0.f;
    #pragma unroll
    for (int d = 0; d < 64; d++) dot += qv[d] * kv[t][d];

    float beta = log1pf(__expf(beta_raw[0]));
    float logit = dot * 0.125f + beta * gb[(size_t)b * Sn * Sn + (size_t)i * Sn + t];

    float m = logit;
    #pragma unroll
    for (int d = 1; d < 64; d <<= 1) m = fmaxf(m, __shfl_xor(m, d));
    if ((t & 63) == 0) wred[0][t >> 6] = m;
    __syncthreads();
    m = fmaxf(wred[0][0], wred[0][1]);
    float e = __expf(logit - m);
    float sm = e;
    #pragma unroll
    for (int d = 1; d < 64; d <<= 1) sm += __shfl_xor(sm, d);
    if ((t & 63) == 0) wred[1][t >> 6] = sm;
    __syncthreads();
    sm = wred[1][0] + wred[1][1];
    p[t] = e / sm;
    __syncthreads();

    for (int l = 0; l < 64; l++) {
        int idx = t + l * 128;
        int j = idx >> 6, d = idx & 63;
        kv[j][d] = v[base + (size_t)j * Cn + d];
    }
    __syncthreads();

    if (t < 64) {
        float o = 0.f;
        #pragma unroll 8
        for (int j = 0; j < 128; j++) o += p[j] * kv[j][t];
        attn16[base + (size_t)i * Cn + t] = f2bf(o);
    }
}

// ---------------- K7: SoT[b][c][s] = (attn16 @ WoT + bo)^T bf16 ----------------
__global__ __launch_bounds__(256) void k_wo(
    const unsigned short* __restrict__ attn16, const unsigned short* __restrict__ WoT,
    const float* __restrict__ bo, unsigned short* __restrict__ SoT)
{
    __shared__ __align__(16) unsigned At32[4096];
    __shared__ __align__(16) unsigned Bt32[4096];
    int t = threadIdx.x;
    int lane = t & 63;
    int wid = t >> 6;
    int ws = wid & 1, wc = wid >> 1;
    int l15 = lane & 15, lg = lane >> 4;
    int b = blockIdx.x, cb = blockIdx.y;

    f32x4 acc[4][4];
    const f32x4 fz = {0.f, 0.f, 0.f, 0.f};
    #pragma unroll
    for (int i = 0; i < 4; i++) {
        #pragma unroll
        for (int j = 0; j < 4; j++) acc[i][j] = fz;
    }

    for (int ks = 0; ks < 8; ks++) {
        stage_bf16tile(attn16 + (size_t)b * 128 * Cn + ks * 64, Cn, 128, At32, t);
        stage_bf16tile(WoT + (size_t)cb * 128 * Cn + ks * 64, Cn, 128, Bt32, t);
        __syncthreads();
        #pragma unroll
        for (int m = 0; m < 2; m++) {
            s16x8 af[4], bfr[4];
            #pragma unroll
            for (int i = 0; i < 4; i++)
                af[i] = *(const s16x8*)((const char*)At32 +
                        lds_off(ws * 64 + i * 16 + l15, m * 32 + lg * 8));
            #pragma unroll
            for (int j = 0; j < 4; j++)
                bfr[j] = *(const s16x8*)((const char*)Bt32 +
                        lds_off(wc * 64 + j * 16 + l15, m * 32 + lg * 8));
            #pragma unroll
            for (int i = 0; i < 4; i++) {
                #pragma unroll
                for (int j = 0; j < 4; j++)
                    acc[i][j] = __builtin_amdgcn_mfma_f32_16x16x32_bf16(
                        af[i], bfr[j], acc[i][j], 0, 0, 0);
            }
        }
        __syncthreads();
    }

    float bvv[4];
    #pragma unroll
    for (int j = 0; j < 4; j++) bvv[j] = bo[cb * 128 + wc * 64 + j * 16 + l15];
    unsigned short* sb = SoT + (size_t)b * Cn * Sn;
    #pragma unroll
    for (int i = 0; i < 4; i++) {
        #pragma unroll
        for (int j = 0; j < 4; j++) {
            int c = cb * 128 + wc * 64 + j * 16 + l15;
            #pragma unroll
            for (int r = 0; r < 4; r++) {
                int s = ws * 64 + i * 16 + lg * 4 + r;
                sb[(size_t)c * Sn + s] = f2bf(acc[i][j][r] + bvv[j]);
            }
        }
    }
}

// ---------------- K8: out[n][c] = sum_s w[n,s]*so[s,c] via MFMA ----------------
__global__ __launch_bounds__(256) void k_out2(
    const unsigned short* __restrict__ wAll, const unsigned short* __restrict__ SoT,
    float* __restrict__ out)
{
    __shared__ __align__(16) unsigned At32[4096];
    __shared__ __align__(16) unsigned Bt32[4096];
    int t = threadIdx.x;
    int lane = t & 63;
    int wid = t >> 6;
    int ws = wid & 1, wc = wid >> 1;
    int l15 = lane & 15, lg = lane >> 4;
    int blk = blockIdx.x;
    int b = blk / (NB128 * 4);
    int rem = blk % (NB128 * 4);
    int rb = rem >> 2;
    int cb = rem & 3;
    int n0 = rb * 128, c0 = cb * 128;
    int nvalid = Nn - n0; if (nvalid > 128) nvalid = 128;
    const unsigned short* wb = wAll + (size_t)b * Nn * Sn;
    const unsigned short* sb = SoT + (size_t)b * Cn * Sn;

    f32x4 acc[4][4];
    const f32x4 fz = {0.f, 0.f, 0.f, 0.f};
    #pragma unroll
    for (int i = 0; i < 4; i++) {
        #pragma unroll
        for (int j = 0; j < 4; j++) acc[i][j] = fz;
    }

    #pragma unroll
    for (int ksi = 0; ksi < 2; ksi++) {
        stage_bf16tile(wb + (size_t)n0 * Sn + ksi * 64, Sn, nvalid, At32, t);
        stage_bf16tile(sb + (size_t)c0 * Sn + ksi * 64, Sn, 128, Bt32, t);
        __syncthreads();
        #pragma unroll
        for (int m = 0; m < 2; m++) {
            s16x8 af[4], bfr[4];
            #pragma unroll
            for (int i = 0; i < 4; i++)
                af[i] = *(const s16x8*)((const char*)At32 +
                        lds_off(ws * 64 + i * 16 + l15, m * 32 + lg * 8));
            #pragma unroll
            for (int j = 0; j < 4; j++)
                bfr[j] = *(const s16x8*)((const char*)Bt32 +
                        lds_off(wc * 64 + j * 16 + l15, m * 32 + lg * 8));
            #pragma unroll
            for (int i = 0; i < 4; i++) {
                #pragma unroll
                for (int j = 0; j < 4; j++)
                    acc[i][j] = __builtin_amdgcn_mfma_f32_16x16x32_bf16(
                        af[i], bfr[j], acc[i][j], 0, 0, 0);
            }
        }
        __syncthreads();
    }

    #pragma unroll
    for (int i = 0; i < 4; i++) {
        #pragma unroll
        for (int r = 0; r < 4; r++) {
            int n = n0 + ws * 64 + i * 16 + lg * 4 + r;
            if (n < Nn) {
                #pragma unroll
                for (int j = 0; j < 4; j++)
                    out[((size_t)b * Nn + n) * Cn + c0 + wc * 64 + j * 16 + l15] =
                        acc[i][j][r];
            }
        }
    }
}

extern "C" void kernel_launch(void* const* d_in, const int* in_sizes, int n_in,
                              void* d_out, int out_size, void* d_ws, size_t ws_size,
                              hipStream_t stream)
{
    const float* x  = (const float*)d_in[0];
    const int* adj  = (const int*)d_in[1];
    const float* av = (const float*)d_in[2];
    const float* Ws = (const float*)d_in[3];
    const float* bs = (const float*)d_in[4];
    const float* Wq = (const float*)d_in[5];
    const float* bq = (const float*)d_in[6];
    const float* Wk = (const float*)d_in[7];
    const float* bk = (const float*)d_in[8];
    const float* Wv = (const float*)d_in[9];
    const float* bv = (const float*)d_in[10];
    const float* Wo = (const float*)d_in[11];
    const float* bo = (const float*)d_in[12];
    const float* br = (const float*)d_in[13];
    float* out = (float*)d_out;
    (void)in_sizes; (void)n_in; (void)out_size; (void)ws_size;

    char* ws = (char*)d_ws;
    size_t off = 0;
    unsigned short* wb16  = (unsigned short*)(ws + off); off += (size_t)Bn * Nn * Sn * 2;
    unsigned short* gwb16 = (unsigned short*)(ws + off); off += (size_t)Bn * Nn * Sn * 2;
    unsigned short* sl16  = (unsigned short*)(ws + off); off += (size_t)Bn * Sn * Cn * 2;
    float* wsum       = (float*)(ws + off); off += 1024;
    float* gb_raw     = (float*)(ws + off); off += (size_t)Bn * Sn * Sn * 4;
    float* gb         = (float*)(ws + off); off += (size_t)Bn * Sn * Sn * 4;
    float* q          = (float*)(ws + off); off += (size_t)Bn * Sn * Cn * 4;
    float* kbuf       = (float*)(ws + off); off += (size_t)Bn * Sn * Cn * 4;
    float* vbuf       = (float*)(ws + off); off += (size_t)Bn * Sn * Cn * 4;
    unsigned short* attn16 = (unsigned short*)(ws + off); off += (size_t)Bn * Sn * Cn * 2;
    unsigned short* WsT = (unsigned short*)(ws + off); off += (size_t)Sn * Cn * 2;
    unsigned short* WT  = (unsigned short*)(ws + off); off += (size_t)4 * Cn * Cn * 2;
    unsigned short* SoT = (unsigned short*)(ws + off); off += (size_t)Bn * Cn * Sn * 2;
    char* U = ws + off;
    int*  deg    = (int*)(U);
    int*  cursor = (int*)(U + 80128);
    int*  offs   = (int*)(U + 160256);
    int2* epack  = (int2*)(U + 240640);
    int*  bsum   = (int*)(U + 2800640);
    float* partialS = (float*)U;
    float* partialG = (float*)(U + (size_t)504 * 65536);

    k_prepW<<<dim3(16, 16, 5), 256, 0, stream>>>(Ws, Wq, Wk, Wv, Wo, WsT, WT,
                                                 (int*)U, wsum);
    k_assign2<<<Bn * NB64, 256, 0, stream>>>(x, WsT, bs, wb16, wsum);

    k_deg<<<(En + 255) / 256, 256, 0, stream>>>(adj, deg);
    k_scanA<<<NSCAN, 1024, 0, stream>>>(deg, offs, bsum);
    k_scanB<<<NSCAN, 1024, 0, stream>>>(offs, bsum);
    k_fill<<<(En + 255) / 256, 256, 0, stream>>>(adj, av, offs, cursor, epack);
    k_gather<<<Nn, 128, 0, stream>>>(wb16, epack, offs, gwb16);

    k_mmS<<<Bn * 4 * S_KB, 256, 0, stream>>>(wb16, x, partialS);
    k_mmG<<<Bn * G_KB, 256, 0, stream>>>(wb16, gwb16, partialG);
    k_reduceSG<<<(Bn * Sn * Cn + Bn * Sn * Sn) / 256, 256, 0, stream>>>(
        partialS, partialG, wsum, sl16, gb_raw);
    k_gb_fin<<<Bn * Sn, 128, 0, stream>>>(gb_raw, gb);

    k_qkv<<<dim3(2, 4, 3), 256, 0, stream>>>(sl16, WT, bq, bk, bv, q, kbuf, vbuf);
    k_attn<<<Bn * Hn * Sn, 128, 0, stream>>>(q, kbuf, vbuf, gb, br, attn16);
    k_wo<<<dim3(2, 4), 256, 0, stream>>>(attn16, WT + (size_t)3 * Cn * Cn, bo, SoT);

    k_out2<<<Bn * NB128 * 4, 256, 0, stream>>>(wb16, SoT, out);
}